// Round 15
// baseline (217.979 us; speedup 1.0000x reference)
//
#include <hip/hip_runtime.h>
#include <hip/hip_bf16.h>

typedef __attribute__((ext_vector_type(8))) short short8;
typedef __attribute__((ext_vector_type(4))) float f32x4;
typedef __attribute__((ext_vector_type(2))) float f32x2;

#define BUK_SHIFT 7
#define BUK_ROWS 128
#define MAXBUK 512
#define ACAP 6144      // per-bucket stride in unpadded arena (max bucket ~4400)
#define CAP2 6144      // per-bucket stride (4B elems) in padded edge array
#define CHUNK 3125     // edges per bin block (512 blocks -> all 256 CUs busy)
#define CHUNK_PAD 3136
#define NW_BLK 128     // wtr blocks inside prep kernel
#define NZ_BLK 40      // tail-zero blocks inside prep kernel

static __device__ __forceinline__ unsigned short f2bf(float f) {
    unsigned u = __float_as_uint(f);
    u += 0x7fffu + ((u >> 16) & 1u);
    return (unsigned short)(u >> 16);
}
static __device__ __forceinline__ unsigned pk2bf(float a, float b) {
    return (unsigned)f2bf(a) | ((unsigned)f2bf(b) << 16);
}

// ---- prep kernel: bin_scatter (blocks [0,nblk)) + weight transpose (next NW_BLK)
//      + d_out tail zeroing (last NZ_BLK). Independent roles, block-uniform branch. ----
__global__ __launch_bounds__(1024) void prep_kernel(const int* __restrict__ rows,
                                                    const int* __restrict__ cols,
                                                    const float* __restrict__ vals,
                                                    int* __restrict__ cursor,
                                                    unsigned int* __restrict__ cc,
                                                    unsigned char* __restrict__ rb,
                                                    int E, int nbuk, int nblk,
                                                    const float* __restrict__ W1,
                                                    const float* __restrict__ W2,
                                                    unsigned short* __restrict__ W1t,
                                                    unsigned short* __restrict__ W2t,
                                                    float* __restrict__ ztail, int nzf4) {
    __shared__ unsigned int scc[CHUNK_PAD];
    __shared__ unsigned char srb[CHUNK_PAD];
    __shared__ int lcnt[MAXBUK], lsc[MAXBUK], lcur[MAXBUK], gbase[MAXBUK];
    const int b = blockIdx.x, tid = threadIdx.x;
    if (b >= nblk) {
        if (b < nblk + NW_BLK) {
            // weight transpose+convert: idx over 2*65536 elems
            int idx = (b - nblk) * 1024 + tid;
            int w = idx >> 16, rem = idx & 65535;
            int k = rem >> 8, n = rem & 255;
            const float* W = w ? W2 : W1;
            unsigned short* Wt = w ? W2t : W1t;
            Wt[n * 256 + k] = f2bf(W[k * 256 + n]);
        } else {
            // zero d_out rows [N, PAD_N)
            float4* z4 = reinterpret_cast<float4*>(ztail);
            int start = (b - nblk - NW_BLK) * 1024 + tid;
            for (int i = start; i < nzf4; i += NZ_BLK * 1024)
                z4[i] = make_float4(0.f, 0.f, 0.f, 0.f);
        }
        return;
    }
    // ---- bin_scatter body ----
    const int s = b * CHUNK, e = s + CHUNK < E ? s + CHUNK : E;
    if (tid < MAXBUK) lcnt[tid] = 0;
    __syncthreads();
    for (int i = s + tid; i < e; i += 1024) atomicAdd(&lcnt[rows[i] >> BUK_SHIFT], 1);
    __syncthreads();
    if (tid < nbuk) gbase[tid] = atomicAdd(&cursor[tid], lcnt[tid]);  // reserve arena runs
    if (tid < MAXBUK) lsc[tid] = lcnt[tid];
    __syncthreads();
    for (int off = 1; off < MAXBUK; off <<= 1) {
        int t = (tid < MAXBUK && tid >= off) ? lsc[tid - off] : 0;
        __syncthreads();
        if (tid < MAXBUK) lsc[tid] += t;
        __syncthreads();
    }
    if (tid < MAXBUK) lcur[tid] = lsc[tid] - lcnt[tid];
    __syncthreads();
    for (int i = s + tid; i < e; i += 1024) {
        int r = rows[i];
        int p = atomicAdd(&lcur[r >> BUK_SHIFT], 1);
        scc[p] = ((unsigned)cols[i] << 16) | (unsigned)f2bf(vals[i]);
        srb[p] = (unsigned char)(r & (BUK_ROWS - 1));
    }
    __syncthreads();
    const int wv = tid >> 6, ln = tid & 63;
    for (int bu = wv; bu < nbuk; bu += 16) {
        const int lo = lsc[bu] - lcnt[bu];
        const int n = lcnt[bu];
        const int gb = bu * ACAP + gbase[bu];
        for (int j = ln; j < n; j += 64) {
            cc[gb + j] = scc[lo + j];
            rb[gb + j] = srb[lo + j];
        }
    }
}

// load a 8-element bf16 fragment for LDS staging; AF32: convert from f32 on the fly
template <int AF32>
static __device__ __forceinline__ uint4 load_frag(const char* p) {
    if (AF32) {
        const float* f = (const float*)p;
        float4 f0 = *reinterpret_cast<const float4*>(f);
        float4 f1 = *reinterpret_cast<const float4*>(f + 4);
        uint4 u;
        u.x = pk2bf(f0.x, f0.y); u.y = pk2bf(f0.z, f0.w);
        u.z = pk2bf(f1.x, f1.y); u.w = pk2bf(f1.z, f1.w);
        return u;
    }
    return *reinterpret_cast<const uint4*>(p);
}

// GEMM device body: S8 [M][256] written as fp8 via slab-major layout [4][M][64].
// Block computes 64 rows x 256 cols with 4 waves; A LDS-staged (XOR-swizzled, dbuf).
template <int AF32>
static __device__ __forceinline__ void gemm_body(const void* __restrict__ Av,
                                                 const unsigned short* __restrict__ Bt,
                                                 unsigned char* __restrict__ S8, int M,
                                                 int bx, unsigned char* lds_raw) {
    unsigned char (*lds)[8192] = reinterpret_cast<unsigned char (*)[8192]>(lds_raw);
    const int esz = AF32 ? 4 : 2;
    const int tid = threadIdx.x;
    const int lane = tid & 63;
    const int wave = tid >> 6;
    const int m0 = bx * 64;
    const int l15 = lane & 15;
    const int q = lane >> 4;
    const int sw = (l15 & 7) << 4;

    const int st_r0 = tid >> 3;
    const int st_c = tid & 7;
    const int st_off0 = st_r0 * 128 + ((st_c ^ (st_r0 & 7)) << 4);
    const int st_r1 = st_r0 + 32;
    const int st_off1 = st_r1 * 128 + ((st_c ^ (st_r1 & 7)) << 4);
    int row0 = m0 + st_r0; row0 = row0 < M ? row0 : 0;
    int row1 = m0 + st_r1; row1 = row1 < M ? row1 : 0;
    const char* s0p = (const char*)Av + ((size_t)row0 * 256 + st_c * 8) * esz;
    const char* s1p = (const char*)Av + ((size_t)row1 * 256 + st_c * 8) * esz;

    const unsigned short* bb = Bt + (size_t)(wave * 64 + l15) * 256 + q * 8;

    f32x4 acc[4][4] = {};

    uint4 s0 = load_frag<AF32>(s0p);
    uint4 s1 = load_frag<AF32>(s1p);
    *reinterpret_cast<uint4*>(&lds[0][st_off0]) = s0;
    *reinterpret_cast<uint4*>(&lds[0][st_off1]) = s1;
    __syncthreads();

#pragma unroll
    for (int it = 0; it < 4; ++it) {
        const int buf = it & 1;
        if (it < 3) {
            s0 = load_frag<AF32>(s0p + (size_t)(it + 1) * 64 * esz);
            s1 = load_frag<AF32>(s1p + (size_t)(it + 1) * 64 * esz);
        }
        const int kk = it * 64;
#pragma unroll
        for (int ks = 0; ks < 2; ++ks) {
            short8 a[4], b[4];
#pragma unroll
            for (int mf = 0; mf < 4; ++mf) {
                int r = mf * 16 + l15;
                a[mf] = *reinterpret_cast<const short8*>(
                    &lds[buf][r * 128 + ((ks * 64 + q * 16) ^ sw)]);
            }
#pragma unroll
            for (int nf = 0; nf < 4; ++nf)
                b[nf] = *reinterpret_cast<const short8*>(bb + (size_t)nf * 16 * 256 + kk + ks * 32);
#pragma unroll
            for (int mf = 0; mf < 4; ++mf)
#pragma unroll
                for (int nf = 0; nf < 4; ++nf)
                    acc[mf][nf] = __builtin_amdgcn_mfma_f32_16x16x32_bf16(b[nf], a[mf], acc[mf][nf], 0, 0, 0);
        }
        if (it < 3) {
            *reinterpret_cast<uint4*>(&lds[buf ^ 1][st_off0]) = s0;
            *reinterpret_cast<uint4*>(&lds[buf ^ 1][st_off1]) = s1;
        }
        __syncthreads();
    }

    const int g4 = q * 4;
#pragma unroll
    for (int mf = 0; mf < 4; ++mf) {
        int m = m0 + mf * 16 + l15;
        if (m < M) {
#pragma unroll
            for (int nf = 0; nf < 4; ++nf) {
                int p = __builtin_amdgcn_cvt_pk_fp8_f32(acc[mf][nf][0], acc[mf][nf][1], 0, false);
                p = __builtin_amdgcn_cvt_pk_fp8_f32(acc[mf][nf][2], acc[mf][nf][3], p, true);
                *reinterpret_cast<int*>(S8 + ((size_t)wave * M + m) * 64 + nf * 16 + g4) = p;
            }
        }
    }
}

// fused layer-1 GEMM (blocks [0,ggrid)) + bucket_pad (blocks [ggrid, ggrid+nbuk)), 256 thr
__global__ __launch_bounds__(256) void padgemm_kernel(const float* __restrict__ x,
                                                      const unsigned short* __restrict__ W1t,
                                                      unsigned char* __restrict__ S8, int M,
                                                      int ggrid,
                                                      const unsigned int* __restrict__ cc,
                                                      const unsigned char* __restrict__ rb,
                                                      const int* __restrict__ cursor,
                                                      unsigned int* __restrict__ cc2,
                                                      int2* __restrict__ rp, int nbuk) {
    __shared__ unsigned char lds_raw[2 * 8192];
    const int bx = blockIdx.x, tid = threadIdx.x;
    if (bx < ggrid) {
        gemm_body<1>(x, W1t, S8, M, bx, lds_raw);
        return;
    }
    // ---- bucket_pad body (stride 256) ----
    int* cnt = reinterpret_cast<int*>(lds_raw);
    int* psc = cnt + BUK_ROWS;
    int* cur = psc + BUK_ROWS;
    const int b = bx - ggrid;
    const int base = b * ACAP;
    int sz = cursor[b];
    if (sz > ACAP) sz = ACAP;   // statistically unreachable guard
    if (tid < BUK_ROWS) cnt[tid] = 0;
    __syncthreads();
    for (int i = tid; i < sz; i += 256) atomicAdd(&cnt[rb[base + i]], 1);
    __syncthreads();
    if (tid < BUK_ROWS) psc[tid] = (cnt[tid] + 7) & ~7;
    __syncthreads();
    for (int off = 1; off < BUK_ROWS; off <<= 1) {
        int t = (tid < BUK_ROWS && tid >= off) ? psc[tid - off] : 0;
        __syncthreads();
        if (tid < BUK_ROWS) psc[tid] += t;
        __syncthreads();
    }
    if (tid < BUK_ROWS) {
        int c = cnt[tid];
        int pc = (c + 7) & ~7;
        int excl = psc[tid] - pc;
        cur[tid] = excl;
        int st = b * CAP2 + excl;
        rp[b * BUK_ROWS + tid] = make_int2(st, st + pc);
        for (int z = c; z < pc; ++z) cc2[(size_t)st + z] = 0u;  // pad slots
    }
    __syncthreads();
    for (int i = tid; i < sz; i += 256) {
        int p = atomicAdd(&cur[rb[base + i]], 1);
        cc2[(size_t)b * CAP2 + p] = cc[base + i];
    }
}

// standalone layer-2 GEMM (A = h bf16)
__global__ __launch_bounds__(256) void gemm_kernel(const unsigned short* __restrict__ A,
                                                   const unsigned short* __restrict__ Bt,
                                                   unsigned char* __restrict__ S8, int M) {
    __shared__ unsigned char lds_raw[2 * 8192];
    gemm_body<0>(A, Bt, S8, M, blockIdx.x, lds_raw);
}

// SpMM over one 64-feature slab (blockIdx.y): wave = 4 rows x 16 lanes; lane owns 4 feats.
// Gathers software-pipelined one full iteration ahead (issue-early/consume-late):
// iter k consumes gathers issued at end of iter k-1 (~1 iteration of latency cover).
// Out-of-row prefetch gathers stay inside workspace and multiply val=0 pads / are discarded.
template <int LAYER2>
__global__ __launch_bounds__(256) void spmm_kernel(const unsigned char* __restrict__ S8,
                                                   const int2* __restrict__ rp,
                                                   const unsigned int* __restrict__ cc,
                                                   const float* __restrict__ bias,
                                                   unsigned short* __restrict__ out_bf,
                                                   float* __restrict__ out_f,
                                                   const int* __restrict__ pos_idx, int N) {
    const int slab = blockIdx.y;
    const int lane = threadIdx.x & 63;
    const int wid = threadIdx.x >> 6;
    const int q = lane >> 4;
    const int l = lane & 15;
    const int row = blockIdx.x * 16 + wid * 4 + q;
    const int2 r = rp[row];
    const unsigned lbyte = (unsigned)l * 4;
    const unsigned char* __restrict__ Sb = S8 + (size_t)slab * N * 64;   // wave-uniform base
    f32x2 a01 = {0.f, 0.f}, a23 = {0.f, 0.f};
    int i = r.x;
    if (i < r.y) {
        uint4 c0 = *reinterpret_cast<const uint4*>(cc + i);
        uint4 c1 = *reinterpret_cast<const uint4*>(cc + i + 4);
        unsigned cw[8] = {c0.x, c0.y, c0.z, c0.w, c1.x, c1.y, c1.z, c1.w};
        unsigned w[8];
#pragma unroll
        for (int e = 0; e < 8; ++e)
            w[e] = *reinterpret_cast<const unsigned*>(Sb + (((cw[e] >> 10) & 0xFFFFFFC0u) | lbyte));
        for (; i < r.y; i += 8) {
            // prefetch next iteration's cc2 words (<=64B past row end stays in bucket slack)
            uint4 n0 = *reinterpret_cast<const uint4*>(cc + i + 8);
            uint4 n1 = *reinterpret_cast<const uint4*>(cc + i + 12);
            // consume current iteration (gathers issued one iteration ago)
#pragma unroll
            for (int e = 0; e < 8; ++e) {
                float v = __uint_as_float(cw[e] << 16);
                f32x2 vv = {v, v};
                a01 += vv * __builtin_amdgcn_cvt_pk_f32_fp8((int)w[e], false);
                a23 += vv * __builtin_amdgcn_cvt_pk_f32_fp8((int)w[e], true);
            }
            // set up & issue next iteration's gathers
            cw[0] = n0.x; cw[1] = n0.y; cw[2] = n0.z; cw[3] = n0.w;
            cw[4] = n1.x; cw[5] = n1.y; cw[6] = n1.z; cw[7] = n1.w;
#pragma unroll
            for (int e = 0; e < 8; ++e)
                w[e] = *reinterpret_cast<const unsigned*>(Sb + (((cw[e] >> 10) & 0xFFFFFFC0u) | lbyte));
        }
    }
    if (row >= N) return;
    const int f = slab * 64 + l * 4;
    float a0 = fmaxf(a01.x + bias[f + 0], 0.f);
    float a1 = fmaxf(a01.y + bias[f + 1], 0.f);
    float a2 = fmaxf(a23.x + bias[f + 2], 0.f);
    float a3 = fmaxf(a23.y + bias[f + 3], 0.f);
    if (LAYER2) {
        int orow = pos_idx[row];
        *reinterpret_cast<float4*>(out_f + (size_t)orow * 256 + f) = make_float4(a0, a1, a2, a3);
    } else {
        ushort4 o;
        o.x = f2bf(a0); o.y = f2bf(a1); o.z = f2bf(a2); o.w = f2bf(a3);
        *reinterpret_cast<ushort4*>(out_bf + (size_t)row * 256 + f) = o;
    }
}

extern "C" void kernel_launch(void* const* d_in, const int* in_sizes, int n_in,
                              void* d_out, int out_size, void* d_ws, size_t ws_size,
                              hipStream_t stream) {
    const float* x        = (const float*)d_in[0];
    const int* adj_rows   = (const int*)d_in[1];
    const int* adj_cols   = (const int*)d_in[2];
    const float* adj_vals = (const float*)d_in[3];
    const int* pos_idx    = (const int*)d_in[5];
    const float* W1       = (const float*)d_in[6];
    const float* b1       = (const float*)d_in[7];
    const float* W2       = (const float*)d_in[8];
    const float* b2       = (const float*)d_in[9];

    const int N = in_sizes[0] / 256;
    const int E = in_sizes[1];
    const int nbuk = (N + BUK_ROWS - 1) >> BUK_SHIFT;       // 391
    const int nblk = (E + CHUNK - 1) / CHUNK;               // 512
    const int nwork = nbuk * BUK_ROWS;                      // 50048

    char* ws = (char*)d_ws;
    size_t off = 0;
    auto alloc = [&](size_t bytes) {
        char* p = ws + off;
        off += (bytes + 255) & ~(size_t)255;
        return p;
    };
    unsigned short* xb   = (unsigned short*)alloc((size_t)N * 256 * 2); // h (bf16) after layer 1
    unsigned char*  sup8 = (unsigned char*)alloc((size_t)N * 256);      // fp8 support, slab layout
    unsigned short* w1t  = (unsigned short*)alloc(256 * 256 * 2);
    unsigned short* w2t  = (unsigned short*)alloc(256 * 256 * 2);
    int2* rp     = (int2*)alloc((size_t)nwork * 8);
    int* cursor  = (int*)alloc((size_t)nbuk * 4);
    unsigned int* cc  = (unsigned int*)alloc((size_t)nbuk * ACAP * 4);  // bucket arena
    unsigned char* rb = (unsigned char*)alloc((size_t)nbuk * ACAP);
    unsigned int* cc2 = (unsigned int*)alloc((size_t)nbuk * CAP2 * 4);
    (void)ws_size; (void)n_in;

    hipMemsetAsync(cursor, 0, (size_t)nbuk * 4, stream);

    // d_out tail rows [N, PAD_N) zeroed inside prep_kernel
    float* ztail = (float*)d_out + (size_t)N * 256;
    const int nzf4 = (out_size - N * 256) / 4;

    // prep: bin_scatter + weight transpose + tail zero
    prep_kernel<<<nblk + NW_BLK + NZ_BLK, 1024, 0, stream>>>(
        adj_rows, adj_cols, adj_vals, cursor, cc, rb, E, nbuk, nblk,
        W1, W2, w1t, w2t, ztail, nzf4);

    const int ggrid = (N + 63) / 64;
    const dim3 sgrid(nwork / 16, 4);

    // layer-1 GEMM (fused f32->bf16) + bucket_pad in one launch
    padgemm_kernel<<<ggrid + nbuk, 256, 0, stream>>>(x, w1t, sup8, N, ggrid,
                                                     cc, rb, cursor, cc2, rp, nbuk);
    spmm_kernel<0><<<sgrid, 256, 0, stream>>>(sup8, rp, cc2, b1, xb, nullptr, nullptr, N);
    // layer 2 (A = h in bf16)
    gemm_kernel<<<ggrid, 256, 0, stream>>>(xb, w2t, sup8, N);
    spmm_kernel<1><<<sgrid, 256, 0, stream>>>(sup8, rp, cc2, b2, nullptr, (float*)d_out, pos_idx, N);
}

// Round 16
// 201.900 us; speedup vs baseline: 1.0796x; 1.0796x over previous
//
#include <hip/hip_runtime.h>
#include <hip/hip_bf16.h>

typedef __attribute__((ext_vector_type(8))) short short8;
typedef __attribute__((ext_vector_type(4))) float f32x4;
typedef __attribute__((ext_vector_type(2))) float f32x2;

#define BUK_SHIFT 7
#define BUK_ROWS 128
#define MAXBUK 512
#define ACAP 6144      // per-bucket stride in unpadded arena (max bucket ~4400)
#define CAP2 6144      // per-bucket stride (4B elems) in padded edge array
#define CHUNK 6250     // edges per bin block
#define CHUNK_PAD 6272
#define NW_BLK 128     // wtr blocks inside prep kernel
#define NZ_BLK 40      // tail-zero blocks inside prep kernel

static __device__ __forceinline__ unsigned short f2bf(float f) {
    unsigned u = __float_as_uint(f);
    u += 0x7fffu + ((u >> 16) & 1u);
    return (unsigned short)(u >> 16);
}
static __device__ __forceinline__ unsigned pk2bf(float a, float b) {
    return (unsigned)f2bf(a) | ((unsigned)f2bf(b) << 16);
}

// ---- prep kernel: bin_scatter (blocks [0,nblk)) + weight transpose (next NW_BLK)
//      + d_out tail zeroing (last NZ_BLK). Independent roles, block-uniform branch. ----
__global__ __launch_bounds__(1024) void prep_kernel(const int* __restrict__ rows,
                                                    const int* __restrict__ cols,
                                                    const float* __restrict__ vals,
                                                    int* __restrict__ cursor,
                                                    unsigned int* __restrict__ cc,
                                                    unsigned char* __restrict__ rb,
                                                    int E, int nbuk, int nblk,
                                                    const float* __restrict__ W1,
                                                    const float* __restrict__ W2,
                                                    unsigned short* __restrict__ W1t,
                                                    unsigned short* __restrict__ W2t,
                                                    float* __restrict__ ztail, int nzf4) {
    __shared__ unsigned int scc[CHUNK_PAD];
    __shared__ unsigned char srb[CHUNK_PAD];
    __shared__ int lcnt[MAXBUK], lsc[MAXBUK], lcur[MAXBUK], gbase[MAXBUK];
    const int b = blockIdx.x, tid = threadIdx.x;
    if (b >= nblk) {
        if (b < nblk + NW_BLK) {
            // weight transpose+convert: idx over 2*65536 elems
            int idx = (b - nblk) * 1024 + tid;
            int w = idx >> 16, rem = idx & 65535;
            int k = rem >> 8, n = rem & 255;
            const float* W = w ? W2 : W1;
            unsigned short* Wt = w ? W2t : W1t;
            Wt[n * 256 + k] = f2bf(W[k * 256 + n]);
        } else {
            // zero d_out rows [N, PAD_N)
            float4* z4 = reinterpret_cast<float4*>(ztail);
            int start = (b - nblk - NW_BLK) * 1024 + tid;
            for (int i = start; i < nzf4; i += NZ_BLK * 1024)
                z4[i] = make_float4(0.f, 0.f, 0.f, 0.f);
        }
        return;
    }
    // ---- bin_scatter body ----
    const int s = b * CHUNK, e = s + CHUNK < E ? s + CHUNK : E;
    if (tid < MAXBUK) lcnt[tid] = 0;
    __syncthreads();
    for (int i = s + tid; i < e; i += 1024) atomicAdd(&lcnt[rows[i] >> BUK_SHIFT], 1);
    __syncthreads();
    if (tid < nbuk) gbase[tid] = atomicAdd(&cursor[tid], lcnt[tid]);  // reserve arena runs
    if (tid < MAXBUK) lsc[tid] = lcnt[tid];
    __syncthreads();
    for (int off = 1; off < MAXBUK; off <<= 1) {
        int t = (tid < MAXBUK && tid >= off) ? lsc[tid - off] : 0;
        __syncthreads();
        if (tid < MAXBUK) lsc[tid] += t;
        __syncthreads();
    }
    if (tid < MAXBUK) lcur[tid] = lsc[tid] - lcnt[tid];
    __syncthreads();
    for (int i = s + tid; i < e; i += 1024) {
        int r = rows[i];
        int p = atomicAdd(&lcur[r >> BUK_SHIFT], 1);
        scc[p] = ((unsigned)cols[i] << 16) | (unsigned)f2bf(vals[i]);
        srb[p] = (unsigned char)(r & (BUK_ROWS - 1));
    }
    __syncthreads();
    const int wv = tid >> 6, ln = tid & 63;
    for (int bu = wv; bu < nbuk; bu += 16) {
        const int lo = lsc[bu] - lcnt[bu];
        const int n = lcnt[bu];
        const int gb = bu * ACAP + gbase[bu];
        for (int j = ln; j < n; j += 64) {
            cc[gb + j] = scc[lo + j];
            rb[gb + j] = srb[lo + j];
        }
    }
}

// load a 8-element bf16 fragment for LDS staging; AF32: convert from f32 on the fly
template <int AF32>
static __device__ __forceinline__ uint4 load_frag(const char* p) {
    if (AF32) {
        const float* f = (const float*)p;
        float4 f0 = *reinterpret_cast<const float4*>(f);
        float4 f1 = *reinterpret_cast<const float4*>(f + 4);
        uint4 u;
        u.x = pk2bf(f0.x, f0.y); u.y = pk2bf(f0.z, f0.w);
        u.z = pk2bf(f1.x, f1.y); u.w = pk2bf(f1.z, f1.w);
        return u;
    }
    return *reinterpret_cast<const uint4*>(p);
}

// GEMM device body: S8 [M][256] written as fp8 via slab-major layout [4][M][64].
// Block computes 64 rows x 256 cols with 4 waves; A LDS-staged (XOR-swizzled, dbuf).
template <int AF32>
static __device__ __forceinline__ void gemm_body(const void* __restrict__ Av,
                                                 const unsigned short* __restrict__ Bt,
                                                 unsigned char* __restrict__ S8, int M,
                                                 int bx, unsigned char* lds_raw) {
    unsigned char (*lds)[8192] = reinterpret_cast<unsigned char (*)[8192]>(lds_raw);
    const int esz = AF32 ? 4 : 2;
    const int tid = threadIdx.x;
    const int lane = tid & 63;
    const int wave = tid >> 6;
    const int m0 = bx * 64;
    const int l15 = lane & 15;
    const int q = lane >> 4;
    const int sw = (l15 & 7) << 4;

    const int st_r0 = tid >> 3;
    const int st_c = tid & 7;
    const int st_off0 = st_r0 * 128 + ((st_c ^ (st_r0 & 7)) << 4);
    const int st_r1 = st_r0 + 32;
    const int st_off1 = st_r1 * 128 + ((st_c ^ (st_r1 & 7)) << 4);
    int row0 = m0 + st_r0; row0 = row0 < M ? row0 : 0;
    int row1 = m0 + st_r1; row1 = row1 < M ? row1 : 0;
    const char* s0p = (const char*)Av + ((size_t)row0 * 256 + st_c * 8) * esz;
    const char* s1p = (const char*)Av + ((size_t)row1 * 256 + st_c * 8) * esz;

    const unsigned short* bb = Bt + (size_t)(wave * 64 + l15) * 256 + q * 8;

    f32x4 acc[4][4] = {};

    uint4 s0 = load_frag<AF32>(s0p);
    uint4 s1 = load_frag<AF32>(s1p);
    *reinterpret_cast<uint4*>(&lds[0][st_off0]) = s0;
    *reinterpret_cast<uint4*>(&lds[0][st_off1]) = s1;
    __syncthreads();

#pragma unroll
    for (int it = 0; it < 4; ++it) {
        const int buf = it & 1;
        if (it < 3) {
            s0 = load_frag<AF32>(s0p + (size_t)(it + 1) * 64 * esz);
            s1 = load_frag<AF32>(s1p + (size_t)(it + 1) * 64 * esz);
        }
        const int kk = it * 64;
#pragma unroll
        for (int ks = 0; ks < 2; ++ks) {
            short8 a[4], b[4];
#pragma unroll
            for (int mf = 0; mf < 4; ++mf) {
                int r = mf * 16 + l15;
                a[mf] = *reinterpret_cast<const short8*>(
                    &lds[buf][r * 128 + ((ks * 64 + q * 16) ^ sw)]);
            }
#pragma unroll
            for (int nf = 0; nf < 4; ++nf)
                b[nf] = *reinterpret_cast<const short8*>(bb + (size_t)nf * 16 * 256 + kk + ks * 32);
#pragma unroll
            for (int mf = 0; mf < 4; ++mf)
#pragma unroll
                for (int nf = 0; nf < 4; ++nf)
                    acc[mf][nf] = __builtin_amdgcn_mfma_f32_16x16x32_bf16(b[nf], a[mf], acc[mf][nf], 0, 0, 0);
        }
        if (it < 3) {
            *reinterpret_cast<uint4*>(&lds[buf ^ 1][st_off0]) = s0;
            *reinterpret_cast<uint4*>(&lds[buf ^ 1][st_off1]) = s1;
        }
        __syncthreads();
    }

    const int g4 = q * 4;
#pragma unroll
    for (int mf = 0; mf < 4; ++mf) {
        int m = m0 + mf * 16 + l15;
        if (m < M) {
#pragma unroll
            for (int nf = 0; nf < 4; ++nf) {
                int p = __builtin_amdgcn_cvt_pk_fp8_f32(acc[mf][nf][0], acc[mf][nf][1], 0, false);
                p = __builtin_amdgcn_cvt_pk_fp8_f32(acc[mf][nf][2], acc[mf][nf][3], p, true);
                *reinterpret_cast<int*>(S8 + ((size_t)wave * M + m) * 64 + nf * 16 + g4) = p;
            }
        }
    }
}

// fused layer-1 GEMM (blocks [0,ggrid)) + bucket_pad (blocks [ggrid, ggrid+nbuk)), 256 thr
__global__ __launch_bounds__(256) void padgemm_kernel(const float* __restrict__ x,
                                                      const unsigned short* __restrict__ W1t,
                                                      unsigned char* __restrict__ S8, int M,
                                                      int ggrid,
                                                      const unsigned int* __restrict__ cc,
                                                      const unsigned char* __restrict__ rb,
                                                      const int* __restrict__ cursor,
                                                      unsigned int* __restrict__ cc2,
                                                      int2* __restrict__ rp, int nbuk) {
    __shared__ unsigned char lds_raw[2 * 8192];
    const int bx = blockIdx.x, tid = threadIdx.x;
    if (bx < ggrid) {
        gemm_body<1>(x, W1t, S8, M, bx, lds_raw);
        return;
    }
    // ---- bucket_pad body (stride 256) ----
    int* cnt = reinterpret_cast<int*>(lds_raw);
    int* psc = cnt + BUK_ROWS;
    int* cur = psc + BUK_ROWS;
    const int b = bx - ggrid;
    const int base = b * ACAP;
    int sz = cursor[b];
    if (sz > ACAP) sz = ACAP;   // statistically unreachable guard
    if (tid < BUK_ROWS) cnt[tid] = 0;
    __syncthreads();
    for (int i = tid; i < sz; i += 256) atomicAdd(&cnt[rb[base + i]], 1);
    __syncthreads();
    if (tid < BUK_ROWS) psc[tid] = (cnt[tid] + 7) & ~7;
    __syncthreads();
    for (int off = 1; off < BUK_ROWS; off <<= 1) {
        int t = (tid < BUK_ROWS && tid >= off) ? psc[tid - off] : 0;
        __syncthreads();
        if (tid < BUK_ROWS) psc[tid] += t;
        __syncthreads();
    }
    if (tid < BUK_ROWS) {
        int c = cnt[tid];
        int pc = (c + 7) & ~7;
        int excl = psc[tid] - pc;
        cur[tid] = excl;
        int st = b * CAP2 + excl;
        rp[b * BUK_ROWS + tid] = make_int2(st, st + pc);
        for (int z = c; z < pc; ++z) cc2[(size_t)st + z] = 0u;  // pad slots
    }
    __syncthreads();
    for (int i = tid; i < sz; i += 256) {
        int p = atomicAdd(&cur[rb[base + i]], 1);
        cc2[(size_t)b * CAP2 + p] = cc[base + i];
    }
}

// standalone layer-2 GEMM (A = h bf16)
__global__ __launch_bounds__(256) void gemm_kernel(const unsigned short* __restrict__ A,
                                                   const unsigned short* __restrict__ Bt,
                                                   unsigned char* __restrict__ S8, int M) {
    __shared__ unsigned char lds_raw[2 * 8192];
    gemm_body<0>(A, Bt, S8, M, blockIdx.x, lds_raw);
}

// SpMM over one 64-feature slab (blockIdx.y): wave = 4 rows x 16 lanes; lane owns 4 feats.
// Wave-uniform slab base + 32-bit per-lane voffset; 8-edge unroll + cc2 prefetch.
// (round-13/14 proven version, 56.5-57 us/layer)
template <int LAYER2>
__global__ __launch_bounds__(256) void spmm_kernel(const unsigned char* __restrict__ S8,
                                                   const int2* __restrict__ rp,
                                                   const unsigned int* __restrict__ cc,
                                                   const float* __restrict__ bias,
                                                   unsigned short* __restrict__ out_bf,
                                                   float* __restrict__ out_f,
                                                   const int* __restrict__ pos_idx, int N) {
    const int slab = blockIdx.y;
    const int lane = threadIdx.x & 63;
    const int wid = threadIdx.x >> 6;
    const int q = lane >> 4;
    const int l = lane & 15;
    const int row = blockIdx.x * 16 + wid * 4 + q;
    const int2 r = rp[row];
    const unsigned lbyte = (unsigned)l * 4;
    const unsigned char* __restrict__ Sb = S8 + (size_t)slab * N * 64;   // wave-uniform base
    f32x2 a01 = {0.f, 0.f}, a23 = {0.f, 0.f};
    int i = r.x;
    if (i < r.y) {
        uint4 c0 = *reinterpret_cast<const uint4*>(cc + i);
        uint4 c1 = *reinterpret_cast<const uint4*>(cc + i + 4);
        for (; i < r.y; i += 8) {
            // prefetch next iteration (<=32B past row end stays in bucket slack)
            uint4 n0 = *reinterpret_cast<const uint4*>(cc + i + 8);
            uint4 n1 = *reinterpret_cast<const uint4*>(cc + i + 12);
            unsigned cw[8] = {c0.x, c0.y, c0.z, c0.w, c1.x, c1.y, c1.z, c1.w};
            unsigned w[8];
#pragma unroll
            for (int e = 0; e < 8; ++e) {
                unsigned off = ((cw[e] >> 10) & 0xFFFFFFC0u) | lbyte;   // (col<<6)+l*4
                w[e] = *reinterpret_cast<const unsigned*>(Sb + off);
            }
#pragma unroll
            for (int e = 0; e < 8; ++e) {
                float v = __uint_as_float(cw[e] << 16);
                f32x2 vv = {v, v};
                a01 += vv * __builtin_amdgcn_cvt_pk_f32_fp8((int)w[e], false);
                a23 += vv * __builtin_amdgcn_cvt_pk_f32_fp8((int)w[e], true);
            }
            c0 = n0; c1 = n1;
        }
    }
    if (row >= N) return;
    const int f = slab * 64 + l * 4;
    float a0 = fmaxf(a01.x + bias[f + 0], 0.f);
    float a1 = fmaxf(a01.y + bias[f + 1], 0.f);
    float a2 = fmaxf(a23.x + bias[f + 2], 0.f);
    float a3 = fmaxf(a23.y + bias[f + 3], 0.f);
    if (LAYER2) {
        int orow = pos_idx[row];
        *reinterpret_cast<float4*>(out_f + (size_t)orow * 256 + f) = make_float4(a0, a1, a2, a3);
    } else {
        ushort4 o;
        o.x = f2bf(a0); o.y = f2bf(a1); o.z = f2bf(a2); o.w = f2bf(a3);
        *reinterpret_cast<ushort4*>(out_bf + (size_t)row * 256 + f) = o;
    }
}

extern "C" void kernel_launch(void* const* d_in, const int* in_sizes, int n_in,
                              void* d_out, int out_size, void* d_ws, size_t ws_size,
                              hipStream_t stream) {
    const float* x        = (const float*)d_in[0];
    const int* adj_rows   = (const int*)d_in[1];
    const int* adj_cols   = (const int*)d_in[2];
    const float* adj_vals = (const float*)d_in[3];
    const int* pos_idx    = (const int*)d_in[5];
    const float* W1       = (const float*)d_in[6];
    const float* b1       = (const float*)d_in[7];
    const float* W2       = (const float*)d_in[8];
    const float* b2       = (const float*)d_in[9];

    const int N = in_sizes[0] / 256;
    const int E = in_sizes[1];
    const int nbuk = (N + BUK_ROWS - 1) >> BUK_SHIFT;       // 391
    const int nblk = (E + CHUNK - 1) / CHUNK;               // 256
    const int nwork = nbuk * BUK_ROWS;                      // 50048

    char* ws = (char*)d_ws;
    size_t off = 0;
    auto alloc = [&](size_t bytes) {
        char* p = ws + off;
        off += (bytes + 255) & ~(size_t)255;
        return p;
    };
    unsigned short* xb   = (unsigned short*)alloc((size_t)N * 256 * 2); // h (bf16) after layer 1
    unsigned char*  sup8 = (unsigned char*)alloc((size_t)N * 256);      // fp8 support, slab layout
    unsigned short* w1t  = (unsigned short*)alloc(256 * 256 * 2);
    unsigned short* w2t  = (unsigned short*)alloc(256 * 256 * 2);
    int2* rp     = (int2*)alloc((size_t)nwork * 8);
    int* cursor  = (int*)alloc((size_t)nbuk * 4);
    unsigned int* cc  = (unsigned int*)alloc((size_t)nbuk * ACAP * 4);  // bucket arena
    unsigned char* rb = (unsigned char*)alloc((size_t)nbuk * ACAP);
    unsigned int* cc2 = (unsigned int*)alloc((size_t)nbuk * CAP2 * 4);
    (void)ws_size; (void)n_in;

    hipMemsetAsync(cursor, 0, (size_t)nbuk * 4, stream);

    // d_out tail rows [N, PAD_N) zeroed inside prep_kernel
    float* ztail = (float*)d_out + (size_t)N * 256;
    const int nzf4 = (out_size - N * 256) / 4;

    // prep: bin_scatter + weight transpose + tail zero
    prep_kernel<<<nblk + NW_BLK + NZ_BLK, 1024, 0, stream>>>(
        adj_rows, adj_cols, adj_vals, cursor, cc, rb, E, nbuk, nblk,
        W1, W2, w1t, w2t, ztail, nzf4);

    const int ggrid = (N + 63) / 64;
    const dim3 sgrid(nwork / 16, 4);

    // layer-1 GEMM (fused f32->bf16) + bucket_pad in one launch
    padgemm_kernel<<<ggrid + nbuk, 256, 0, stream>>>(x, w1t, sup8, N, ggrid,
                                                     cc, rb, cursor, cc2, rp, nbuk);
    spmm_kernel<0><<<sgrid, 256, 0, stream>>>(sup8, rp, cc2, b1, xb, nullptr, nullptr, N);
    // layer 2 (A = h in bf16)
    gemm_kernel<<<ggrid, 256, 0, stream>>>(xb, w2t, sup8, N);
    spmm_kernel<1><<<sgrid, 256, 0, stream>>>(sup8, rp, cc2, b2, nullptr, (float*)d_out, pos_idx, N);
}